// Round 5
// baseline (243.493 us; speedup 1.0000x reference)
//
#include <hip/hip_runtime.h>
#include <hip/hip_fp16.h>
#include <math.h>

constexpr int kNodes   = 40000;
constexpr int kEdges   = 640000;
constexpr int kEmb     = 128;
constexpr int kOut     = 256;
constexpr int kTargets = 12;
constexpr int kRadial  = 6;

typedef float        f32x4 __attribute__((ext_vector_type(4)));
typedef unsigned int u32x4 __attribute__((ext_vector_type(4)));

__device__ __forceinline__ unsigned short f2h(float f) {
  return __half_as_ushort(__float2half(f));   // RTNE
}
__device__ __forceinline__ void mfma_f16(f32x4& c, u32x4 a, u32x4 b) {
  asm volatile("v_mfma_f32_16x16x32_f16 %0, %1, %2, %0" : "+v"(c) : "v"(a), "v"(b));
}

// ---------------------------------------------------------------------------
// CSR build (multi-block, coalesced; int atomics only)
// ---------------------------------------------------------------------------
__global__ __launch_bounds__(256) void zero_counts(int* __restrict__ c) {
  const int i = blockIdx.x * 256 + threadIdx.x;
  if (i < kNodes) c[i] = 0;
}

__global__ __launch_bounds__(256) void hist_kernel(const int* __restrict__ idnb,
                                                   int* __restrict__ counts) {
  const int e = blockIdx.x * 256 + threadIdx.x;
  if (e < kEdges) atomicAdd(&counts[idnb[e]], 1);
}

__global__ __launch_bounds__(256) void scan_pass1(const int* __restrict__ counts,
                                                  int* __restrict__ bsum) {
  __shared__ int sm[256];
  const int idx = blockIdx.x * 256 + threadIdx.x;
  sm[threadIdx.x] = (idx < kNodes) ? counts[idx] : 0;
  __syncthreads();
  for (int d = 128; d > 0; d >>= 1) {
    if (threadIdx.x < d) sm[threadIdx.x] += sm[threadIdx.x + d];
    __syncthreads();
  }
  if (threadIdx.x == 0) bsum[blockIdx.x] = sm[0];
}

// Fused (old pass2+pass3): each block reduces the preceding block-sums itself
// (nblk=157 ints, L2-resident), then local scan.
__global__ __launch_bounds__(256) void scan_pass3(const int* __restrict__ counts,
                                                  const int* __restrict__ bsum,
                                                  int* __restrict__ offs,
                                                  int* __restrict__ next,
                                                  int nblk) {
  __shared__ int sm[256];
  __shared__ int base;
  const int t = threadIdx.x;
  sm[t] = (t < nblk && t < (int)blockIdx.x) ? bsum[t] : 0;
  __syncthreads();
  for (int d = 128; d > 0; d >>= 1) {
    if (t < d) sm[t] += sm[t + d];
    __syncthreads();
  }
  if (t == 0) base = sm[0];
  __syncthreads();

  const int idx = blockIdx.x * 256 + t;
  const int v = (idx < kNodes) ? counts[idx] : 0;
  sm[t] = v;
  __syncthreads();
  for (int d = 1; d < 256; d <<= 1) {
    const int xsh = (t >= d) ? sm[t - d] : 0;
    __syncthreads();
    sm[t] += xsh;
    __syncthreads();
  }
  if (idx < kNodes) {
    const int e = base + sm[t] - v;   // exclusive prefix
    offs[idx] = e;
    next[idx] = e;
  }
  if (blockIdx.x == 0 && t == 0) offs[kNodes] = kEdges;
}

__global__ __launch_bounds__(256) void fill_kernel(const int* __restrict__ idnb,
                                                   int* __restrict__ next,
                                                   int* __restrict__ edgeIdx) {
  const int e = blockIdx.x * 256 + threadIdx.x;
  if (e < kEdges) {
    const int p = atomicAdd(&next[idnb[e]], 1);
    edgeIdx[p] = e;
  }
}

// ---------------------------------------------------------------------------
// Weight prep: f32 -> fp16, transposed to [N][K] row-major.
// ---------------------------------------------------------------------------
__global__ __launch_bounds__(256) void prep_weights(
    const float* __restrict__ Wup, const float* __restrict__ Wmlp,
    const float* __restrict__ Wfin,
    unsigned short* __restrict__ WtUp, unsigned short* __restrict__ WtM,
    unsigned short* __restrict__ WtFin) {
  const int id = blockIdx.x * 256 + threadIdx.x;
  if (id < 256 * 128) {
    const int n = id >> 7, k = id & 127;
    WtUp[id] = f2h(Wup[k * 256 + n]);
    return;
  }
  const int id2 = id - 256 * 128;
  if (id2 < 3 * 256 * 256) {
    const int l = id2 >> 16, rem = id2 & 65535, n = rem >> 8, k = rem & 255;
    WtM[id2] = f2h(Wmlp[l * 65536 + k * 256 + n]);
    return;
  }
  const int id3 = id2 - 3 * 256 * 256;
  if (id3 < 16 * 256) {
    const int n = id3 >> 8, k = id3 & 255;
    WtFin[id3] = (n < kTargets) ? f2h(Wfin[k * kTargets + n]) : (unsigned short)0;
  }
}

// ---------------------------------------------------------------------------
// Gather: 32 lanes per node; 1-deep software pipeline so the next edge's
// x-row (HBM ~900cy) loads while the current edge is consumed.
// ---------------------------------------------------------------------------
__global__ __launch_bounds__(256) void gather_kernel(
    const float* __restrict__ x, const float* __restrict__ rbf,
    const int* __restrict__ offs, const int* __restrict__ edgeIdx,
    const float* __restrict__ W_rbf, unsigned short* __restrict__ pooled) {
  __shared__ float wLds[kRadial * kEmb];
  for (int i = threadIdx.x; i < kRadial * kEmb; i += 256) wLds[i] = W_rbf[i];
  __syncthreads();

  const int sub = threadIdx.x & 31;
  const int n   = blockIdx.x * 8 + (threadIdx.x >> 5);

  float4 w[kRadial];
#pragma unroll
  for (int j = 0; j < kRadial; ++j)
    w[j] = *(const float4*)(wLds + j * kEmb + sub * 4);

  const int beg = offs[n], end = offs[n + 1];
  float4 acc = make_float4(0.f, 0.f, 0.f, 0.f);

  if (beg < end) {
    // Prologue: load edge[beg].
    int e = edgeIdx[beg];
    float4 xv = *(const float4*)(x + (size_t)e * kEmb + sub * 4);
    const float* rr = rbf + (size_t)e * kRadial;
    float2 ra = *(const float2*)(rr);
    float2 rb = *(const float2*)(rr + 2);
    float2 rc = *(const float2*)(rr + 4);

    for (int i = beg; i < end; ++i) {
      // Prefetch edge i+1 (loads overlap the compute below).
      float4 xv_n;
      float2 na, nb, nc;
      const bool more = (i + 1 < end);
      if (more) {
        const int en = edgeIdx[i + 1];
        xv_n = *(const float4*)(x + (size_t)en * kEmb + sub * 4);
        const float* rn = rbf + (size_t)en * kRadial;
        na = *(const float2*)(rn);
        nb = *(const float2*)(rn + 2);
        nc = *(const float2*)(rn + 4);
      }
      // Consume edge i.
      float4 g;
      g.x = ra.x * w[0].x + ra.y * w[1].x + rb.x * w[2].x + rb.y * w[3].x +
            rc.x * w[4].x + rc.y * w[5].x;
      g.y = ra.x * w[0].y + ra.y * w[1].y + rb.x * w[2].y + rb.y * w[3].y +
            rc.x * w[4].y + rc.y * w[5].y;
      g.z = ra.x * w[0].z + ra.y * w[1].z + rb.x * w[2].z + rb.y * w[3].z +
            rc.x * w[4].z + rc.y * w[5].z;
      g.w = ra.x * w[0].w + ra.y * w[1].w + rb.x * w[2].w + rb.y * w[3].w +
            rc.x * w[4].w + rc.y * w[5].w;
      acc.x += g.x * xv.x;
      acc.y += g.y * xv.y;
      acc.z += g.z * xv.z;
      acc.w += g.w * xv.w;
      if (more) {
        xv = xv_n;
        ra = na; rb = nb; rc = nc;
      }
    }
  }
  ushort4 hv;
  hv.x = f2h(acc.x);
  hv.y = f2h(acc.y);
  hv.z = f2h(acc.z);
  hv.w = f2h(acc.w);
  *(ushort4*)(pooled + (size_t)n * kEmb + sub * 4) = hv;
}

// ---------------------------------------------------------------------------
// Fused node MLP: 64 rows/block, 625 blocks, 256 thr (4 waves, col-split).
// ---------------------------------------------------------------------------
__global__ __launch_bounds__(256) void fused_mlp(
    const unsigned short* __restrict__ pooled,
    const unsigned short* __restrict__ WtUp,
    const unsigned short* __restrict__ WtM,
    const unsigned short* __restrict__ WtFin,
    const float* __restrict__ b_mlp, float* __restrict__ out) {
  __shared__ unsigned short act[64][266];     // odd word-pitch: conflict-light
  __shared__ unsigned short sB[2][256][40];   // padded rows

  const int tid     = threadIdx.x;
  const int rowBase = blockIdx.x * 64;
  const int w    = tid >> 6;
  const int lane = tid & 63;
  const int lrow = lane & 15;
  const int kgrp = lane >> 4;

  // Stage pooled -> act (64 x 128 fp16).
#pragma unroll
  for (int p = 0; p < 4; ++p) {
    const int q = p * 256 + tid;
    const int r = q >> 4, c = q & 15;
    *(u32x4*)&act[r][c * 8] =
        *(const u32x4*)(pooled + (size_t)(rowBase + r) * kEmb + c * 8);
  }
  __syncthreads();

  for (int l = 0; l < 4; ++l) {
    const int K = (l == 0) ? 128 : 256;
    const int nc = K >> 5;
    const unsigned short* W = (l == 0) ? WtUp : WtM + (size_t)(l - 1) * 65536;

#pragma unroll
    for (int p = 0; p < 4; ++p) {
      const int q = p * 256 + tid;
      const int n = q >> 2, c4 = q & 3;
      *(u32x4*)&sB[0][n][c4 * 8] = *(const u32x4*)(W + (size_t)n * K + c4 * 8);
    }
    __syncthreads();

    f32x4 acc[4][4];
#pragma unroll
    for (int i = 0; i < 4; ++i)
#pragma unroll
      for (int j = 0; j < 4; ++j) acc[i][j] = f32x4{0.f, 0.f, 0.f, 0.f};

    for (int c = 0; c < nc; ++c) {
      if (c + 1 < nc) {
        const int kb = (c + 1) * 32;
#pragma unroll
        for (int p = 0; p < 4; ++p) {
          const int q = p * 256 + tid;
          const int n = q >> 2, c4 = q & 3;
          *(u32x4*)&sB[(c + 1) & 1][n][c4 * 8] =
              *(const u32x4*)(W + (size_t)n * K + kb + c4 * 8);
        }
      }
      u32x4 a[4];
#pragma unroll
      for (int i = 0; i < 4; ++i)
        a[i] = *(const u32x4*)&act[i * 16 + lrow][c * 32 + kgrp * 8];
#pragma unroll
      for (int j = 0; j < 4; ++j) {
        const u32x4 b = *(const u32x4*)&sB[c & 1][w * 64 + j * 16 + lrow][kgrp * 8];
#pragma unroll
        for (int i = 0; i < 4; ++i) mfma_f16(acc[i][j], a[i], b);
      }
      __syncthreads();
    }

    const float* bias = (l >= 1) ? b_mlp + (size_t)(l - 1) * kOut : nullptr;
#pragma unroll
    for (int j = 0; j < 4; ++j) {
      const int col = w * 64 + j * 16 + lrow;
      const float bj = (l >= 1) ? bias[col] : 0.f;
#pragma unroll
      for (int i = 0; i < 4; ++i) {
#pragma unroll
        for (int r = 0; r < 4; ++r) {
          float v = acc[i][j][r];
          if (l >= 1) {
            v += bj;
            v = v / (1.f + __expf(-v));   // silu
          }
          act[i * 16 + kgrp * 4 + r][col] = f2h(v);
        }
      }
    }
    __syncthreads();
  }

  // Final projection: act[64,256] @ WtFin^T[16,256]; wave w covers its k-slice.
  unsigned short (*sWf)[266] = (unsigned short(*)[266]) & sB[0][0][0];
  float (*sPart)[64][17]     = (float(*)[64][17]) & sB[1][0][0];
#pragma unroll
  for (int p = 0; p < 2; ++p) {
    const int q = p * 256 + tid;
    const int n = q >> 5, c = q & 31;
    *(u32x4*)&sWf[n][c * 8] = *(const u32x4*)(WtFin + (size_t)n * 256 + c * 8);
  }
  __syncthreads();

  f32x4 accF[4];
#pragma unroll
  for (int i = 0; i < 4; ++i) accF[i] = f32x4{0.f, 0.f, 0.f, 0.f};
#pragma unroll
  for (int s = 0; s < 2; ++s) {
    const int cc = w * 2 + s;
    const u32x4 b = *(const u32x4*)&sWf[lrow][cc * 32 + kgrp * 8];
#pragma unroll
    for (int i = 0; i < 4; ++i) {
      const u32x4 a = *(const u32x4*)&act[i * 16 + lrow][cc * 32 + kgrp * 8];
      mfma_f16(accF[i], a, b);
    }
  }
#pragma unroll
  for (int i = 0; i < 4; ++i)
#pragma unroll
    for (int r = 0; r < 4; ++r)
      sPart[w][i * 16 + kgrp * 4 + r][lrow] = accF[i][r];
  __syncthreads();

  for (int q = tid; q < 64 * kTargets; q += 256) {
    const int r = q / kTargets, t = q % kTargets;
    out[(size_t)(rowBase + r) * kTargets + t] =
        sPart[0][r][t] + sPart[1][r][t] + sPart[2][r][t] + sPart[3][r][t];
  }
}

// ---------------------------------------------------------------------------
extern "C" void kernel_launch(void* const* d_in, const int* in_sizes, int n_in,
                              void* d_out, int out_size, void* d_ws, size_t ws_size,
                              hipStream_t stream) {
  const float* x      = (const float*)d_in[1];
  const float* rbf    = (const float*)d_in[2];
  const int*   idnb   = (const int*)d_in[3];
  const float* W_rbf  = (const float*)d_in[4];
  const float* W_up   = (const float*)d_in[5];
  const float* W_mlp  = (const float*)d_in[6];
  const float* b_mlp  = (const float*)d_in[7];
  const float* W_fin  = (const float*)d_in[8];
  float* out = (float*)d_out;

  char* wp = (char*)d_ws;
  auto alloc = [&](size_t bytes) -> void* {
    void* r = wp;
    wp += (bytes + 255) & ~(size_t)255;
    return r;
  };
  unsigned short* pooled = (unsigned short*)alloc((size_t)kNodes * kEmb * 2);
  unsigned short* WtUp   = (unsigned short*)alloc(256 * 128 * 2);
  unsigned short* WtM    = (unsigned short*)alloc(3 * 256 * 256 * 2);
  unsigned short* WtFin  = (unsigned short*)alloc(16 * 256 * 2);
  int* counts  = (int*)alloc((size_t)kNodes * 4);
  int* offs    = (int*)alloc((size_t)(kNodes + 8) * 4);
  int* next    = (int*)alloc((size_t)kNodes * 4);
  int* edgeIdx = (int*)alloc((size_t)kEdges * 4);
  int* bsum    = (int*)alloc(256 * 4);

  constexpr int nScanBlk = (kNodes + 255) / 256;  // 157

  // CSR build (5 launches).
  zero_counts<<<nScanBlk, 256, 0, stream>>>(counts);
  hist_kernel<<<kEdges / 256, 256, 0, stream>>>(idnb, counts);
  scan_pass1<<<nScanBlk, 256, 0, stream>>>(counts, bsum);
  scan_pass3<<<nScanBlk, 256, 0, stream>>>(counts, bsum, offs, next, nScanBlk);
  fill_kernel<<<kEdges / 256, 256, 0, stream>>>(idnb, next, edgeIdx);

  // Weight prep (independent of CSR).
  constexpr int prepElems = 256 * 128 + 3 * 256 * 256 + 16 * 256;
  prep_weights<<<(prepElems + 255) / 256, 256, 0, stream>>>(
      W_up, W_mlp, W_fin, WtUp, WtM, WtFin);

  // Edge gather -> pooled fp16 (software-pipelined).
  gather_kernel<<<kNodes / 8, 256, 0, stream>>>(x, rbf, offs, edgeIdx, W_rbf,
                                                pooled);

  // Fused node MLP + final projection.
  fused_mlp<<<kNodes / 64, 256, 0, stream>>>(pooled, WtUp, WtM, WtFin, b_mlp,
                                             out);
}

// Round 7
// 221.175 us; speedup vs baseline: 1.1009x; 1.1009x over previous
//
#include <hip/hip_runtime.h>
#include <hip/hip_fp16.h>
#include <math.h>

constexpr int kNodes   = 40000;
constexpr int kEdges   = 640000;
constexpr int kEmb     = 128;
constexpr int kOut     = 256;
constexpr int kTargets = 12;
constexpr int kRadial  = 6;

typedef float        f32x4 __attribute__((ext_vector_type(4)));
typedef unsigned int u32x4 __attribute__((ext_vector_type(4)));

// Address-space-qualified pointer types for global_load_lds.
typedef __attribute__((address_space(1))) const void gvoid;
typedef __attribute__((address_space(3))) void       lvoid;

__device__ __forceinline__ unsigned short f2h(float f) {
  return __half_as_ushort(__float2half(f));   // RTNE
}
__device__ __forceinline__ void mfma_f16(f32x4& c, u32x4 a, u32x4 b) {
  asm volatile("v_mfma_f32_16x16x32_f16 %0, %1, %2, %0" : "+v"(c) : "v"(a), "v"(b));
}

// ---------------------------------------------------------------------------
// CSR build (multi-block, coalesced; int atomics only)
// ---------------------------------------------------------------------------
__global__ __launch_bounds__(256) void hist_kernel(const int* __restrict__ idnb,
                                                   int* __restrict__ counts) {
  const int e = blockIdx.x * 256 + threadIdx.x;
  if (e < kEdges) atomicAdd(&counts[idnb[e]], 1);
}

__global__ __launch_bounds__(256) void scan_pass1(const int* __restrict__ counts,
                                                  int* __restrict__ bsum) {
  __shared__ int sm[256];
  const int idx = blockIdx.x * 256 + threadIdx.x;
  sm[threadIdx.x] = (idx < kNodes) ? counts[idx] : 0;
  __syncthreads();
  for (int d = 128; d > 0; d >>= 1) {
    if (threadIdx.x < d) sm[threadIdx.x] += sm[threadIdx.x + d];
    __syncthreads();
  }
  if (threadIdx.x == 0) bsum[blockIdx.x] = sm[0];
}

// Each block reduces the preceding block-sums itself (L2-resident), then local scan.
__global__ __launch_bounds__(256) void scan_pass3(const int* __restrict__ counts,
                                                  const int* __restrict__ bsum,
                                                  int* __restrict__ offs,
                                                  int* __restrict__ next,
                                                  int nblk) {
  __shared__ int sm[256];
  __shared__ int base;
  const int t = threadIdx.x;
  sm[t] = (t < nblk && t < (int)blockIdx.x) ? bsum[t] : 0;
  __syncthreads();
  for (int d = 128; d > 0; d >>= 1) {
    if (t < d) sm[t] += sm[t + d];
    __syncthreads();
  }
  if (t == 0) base = sm[0];
  __syncthreads();

  const int idx = blockIdx.x * 256 + t;
  const int v = (idx < kNodes) ? counts[idx] : 0;
  sm[t] = v;
  __syncthreads();
  for (int d = 1; d < 256; d <<= 1) {
    const int xsh = (t >= d) ? sm[t - d] : 0;
    __syncthreads();
    sm[t] += xsh;
    __syncthreads();
  }
  if (idx < kNodes) {
    const int e = base + sm[t] - v;   // exclusive prefix
    offs[idx] = e;
    next[idx] = e;
  }
  if (blockIdx.x == 0 && t == 0) offs[kNodes] = kEdges;
}

__global__ __launch_bounds__(256) void fill_kernel(const int* __restrict__ idnb,
                                                   int* __restrict__ next,
                                                   int* __restrict__ edgeIdx) {
  const int e = blockIdx.x * 256 + threadIdx.x;
  if (e < kEdges) {
    const int p = atomicAdd(&next[idnb[e]], 1);
    edgeIdx[p] = e;
  }
}

// ---------------------------------------------------------------------------
// Weight prep: f32 -> fp16, rearranged into MFMA fragment order ("image"):
// per 32-k chunk c (16 KB), per wave w, per col-fragment j, lane l:
//   shorts[ c*8192 + w*2048 + j*512 + l*8 + e ] = W[k][n]
//   with n = w*64 + j*16 + (l&15),  k = c*32 + (l>>4)*8 + e.
// A lane's 16 B sits at base + l*16 -> linear global_load_lds staging AND
// conflict-free lane-contiguous ds_read_b128 consumption.
// Also zeroes the CSR counts array (folds a launch).
// ---------------------------------------------------------------------------
__global__ __launch_bounds__(256) void prep_weights(
    const float* __restrict__ Wup, const float* __restrict__ Wmlp,
    const float* __restrict__ Wfin,
    unsigned short* __restrict__ WtUp, unsigned short* __restrict__ WtM,
    unsigned short* __restrict__ WtFin, int* __restrict__ counts) {
  const int id = blockIdx.x * 256 + threadIdx.x;
  if (id < kNodes) counts[id] = 0;

  if (id < 32768) {                       // W_up image (K=128 -> 4 chunks)
    const int e = id & 7, u = id >> 3;
    const int l = u & 63, j = (u >> 6) & 3, wv = (u >> 8) & 3, c = u >> 10;
    const int n = wv * 64 + j * 16 + (l & 15);
    const int k = c * 32 + (l >> 4) * 8 + e;
    WtUp[id] = f2h(Wup[k * 256 + n]);
    return;
  }
  const int id2 = id - 32768;
  if (id2 < 3 * 65536) {                  // W_mlp images (K=256 -> 8 chunks)
    const int L = id2 >> 16, r = id2 & 65535;
    const int e = r & 7, u = r >> 3;
    const int l = u & 63, j = (u >> 6) & 3, wv = (u >> 8) & 3, c = u >> 10;
    const int n = wv * 64 + j * 16 + (l & 15);
    const int k = c * 32 + (l >> 4) * 8 + e;
    WtM[id2] = f2h(Wmlp[L * 65536 + k * 256 + n]);
    return;
  }
  const int id3 = id2 - 3 * 65536;
  if (id3 < 16 * 256) {                   // W_final^T, targets padded 12->16
    const int n = id3 >> 8, k = id3 & 255;
    WtFin[id3] = (n < kTargets) ? f2h(Wfin[k * kTargets + n]) : (unsigned short)0;
  }
}

// ---------------------------------------------------------------------------
// Gather: 32 lanes per node; nontemporal x loads (read-once 327 MB stream,
// keep L2/L3 for edgeIdx/rbf).
// ---------------------------------------------------------------------------
__global__ __launch_bounds__(256) void gather_kernel(
    const float* __restrict__ x, const float* __restrict__ rbf,
    const int* __restrict__ offs, const int* __restrict__ edgeIdx,
    const float* __restrict__ W_rbf, unsigned short* __restrict__ pooled) {
  __shared__ float wLds[kRadial * kEmb];
  for (int i = threadIdx.x; i < kRadial * kEmb; i += 256) wLds[i] = W_rbf[i];
  __syncthreads();

  const int sub = threadIdx.x & 31;
  const int n   = blockIdx.x * 8 + (threadIdx.x >> 5);

  f32x4 w[kRadial];
#pragma unroll
  for (int j = 0; j < kRadial; ++j)
    w[j] = *(const f32x4*)(wLds + j * kEmb + sub * 4);

  const int beg = offs[n], end = offs[n + 1];
  f32x4 acc = {0.f, 0.f, 0.f, 0.f};

  for (int i = beg; i < end; ++i) {
    const int e = edgeIdx[i];
    const float* rr = rbf + (size_t)e * kRadial;
    const float r0 = rr[0], r1 = rr[1], r2 = rr[2];
    const float r3 = rr[3], r4 = rr[4], r5 = rr[5];
    const f32x4 xv =
        __builtin_nontemporal_load((const f32x4*)(x + (size_t)e * kEmb + sub * 4));
    const f32x4 g = r0 * w[0] + r1 * w[1] + r2 * w[2] +
                    r3 * w[3] + r4 * w[4] + r5 * w[5];
    acc += g * xv;
  }
  ushort4 hv;
  hv.x = f2h(acc.x);
  hv.y = f2h(acc.y);
  hv.z = f2h(acc.z);
  hv.w = f2h(acc.w);
  *(ushort4*)(pooled + (size_t)n * kEmb + sub * 4) = hv;
}

// ---------------------------------------------------------------------------
// Fused node MLP, async-staged weights.
// Each wave stages ONLY the fragments it consumes (global_load_lds width 16
// into its private 4 KB sB region) -> zero cross-wave deps on sB -> NO
// per-chunk barriers; counted vmcnt(4) keeps next chunk's DMA in flight.
// Barriers only bracket the act rewrite (2/layer).
// ---------------------------------------------------------------------------
__global__ __launch_bounds__(256) void fused_mlp(
    const unsigned short* __restrict__ pooled,
    const unsigned short* __restrict__ WtUp,
    const unsigned short* __restrict__ WtM,
    const unsigned short* __restrict__ WtFin,
    const float* __restrict__ b_mlp, float* __restrict__ out) {
  __shared__ unsigned short act[64][266];   // odd word-pitch: conflict-light
  __shared__ unsigned short sB[2][8192];    // 2 x 16 KB, linear fragment order

  const int tid     = threadIdx.x;
  const int rowBase = blockIdx.x * 64;
  const int w    = tid >> 6;
  const int lane = tid & 63;
  const int lrow = lane & 15;
  const int kgrp = lane >> 4;

  // Stage pooled -> act (64 x 128 fp16).
#pragma unroll
  for (int p = 0; p < 4; ++p) {
    const int q = p * 256 + tid;
    const int r = q >> 4, c = q & 15;
    *(u32x4*)&act[r][c * 8] =
        *(const u32x4*)(pooled + (size_t)(rowBase + r) * kEmb + c * 8);
  }
  __syncthreads();

  for (int l = 0; l < 4; ++l) {
    const int nc = (l == 0) ? 4 : 8;
    const unsigned short* W = (l == 0) ? WtUp : WtM + (size_t)(l - 1) * 65536;

    // Preload bias into VGPRs and pin, so the k-loop's vmcnt counts only
    // our stage DMAs (no compiler-hoisted loads mixing into the count).
    float bj[4] = {0.f, 0.f, 0.f, 0.f};
    if (l >= 1) {
      const float* bias = b_mlp + (size_t)(l - 1) * kOut;
#pragma unroll
      for (int j = 0; j < 4; ++j) bj[j] = bias[w * 64 + j * 16 + lrow];
      asm volatile("" ::"v"(bj[0]), "v"(bj[1]), "v"(bj[2]), "v"(bj[3]));
    }

    // Prologue: stage chunk 0 -> buf 0 (wave-private fragments).
#pragma unroll
    for (int j = 0; j < 4; ++j)
      __builtin_amdgcn_global_load_lds(
          (gvoid*)(W + w * 2048 + j * 512 + lane * 8),
          (lvoid*)&sB[0][w * 2048 + j * 512], 16, 0, 0);

    f32x4 acc[4][4];
#pragma unroll
    for (int i = 0; i < 4; ++i)
#pragma unroll
      for (int j = 0; j < 4; ++j) acc[i][j] = f32x4{0.f, 0.f, 0.f, 0.f};

    int buf = 0;
    for (int c = 0; c < nc; ++c) {
      if (c + 1 < nc) {
        const unsigned short* Wn = W + (size_t)(c + 1) * 8192;
#pragma unroll
        for (int j = 0; j < 4; ++j)
          __builtin_amdgcn_global_load_lds(
              (gvoid*)(Wn + w * 2048 + j * 512 + lane * 8),
              (lvoid*)&sB[buf ^ 1][w * 2048 + j * 512], 16, 0, 0);
        asm volatile("s_waitcnt vmcnt(4)" ::: "memory");  // chunk c landed
      } else {
        asm volatile("s_waitcnt vmcnt(0)" ::: "memory");
      }
      u32x4 a[4], b[4];
#pragma unroll
      for (int i = 0; i < 4; ++i)
        a[i] = *(const u32x4*)&act[i * 16 + lrow][c * 32 + kgrp * 8];
#pragma unroll
      for (int j = 0; j < 4; ++j)
        b[j] = *(const u32x4*)&sB[buf][w * 2048 + j * 512 + lane * 8];
      __builtin_amdgcn_s_setprio(1);
#pragma unroll
      for (int j = 0; j < 4; ++j)
#pragma unroll
        for (int i = 0; i < 4; ++i) mfma_f16(acc[i][j], a[i], b[j]);
      __builtin_amdgcn_s_setprio(0);
      buf ^= 1;
    }

    __syncthreads();   // all waves done reading act for this layer
#pragma unroll
    for (int j = 0; j < 4; ++j) {
      const int col = w * 64 + j * 16 + lrow;
#pragma unroll
      for (int i = 0; i < 4; ++i) {
#pragma unroll
        for (int r = 0; r < 4; ++r) {
          float v = acc[i][j][r];
          if (l >= 1) {
            v += bj[j];
            v = v / (1.f + __expf(-v));   // silu
          }
          act[i * 16 + kgrp * 4 + r][col] = f2h(v);
        }
      }
    }
    __syncthreads();
  }

  // Final projection: act[64,256] @ WtFin^T[16,256]; wave w covers its k-slice.
  // sPart MUST have inner dim 16: the MFMA epilogue writes cols 0..15
  // (12 real targets + 4 zero-padded). [64][16] floats = exactly 16 KB = sB[1].
  unsigned short (*sWf)[266] = (unsigned short(*)[266]) & sB[0][0];  // 8.5 KB
  float (*sPart)[64][16]     = (float(*)[64][16]) & sB[1][0];        // 16 KB
#pragma unroll
  for (int p = 0; p < 2; ++p) {
    const int q = p * 256 + tid;
    const int n = q >> 5, c = q & 31;
    *(u32x4*)&sWf[n][c * 8] = *(const u32x4*)(WtFin + (size_t)n * 256 + c * 8);
  }
  __syncthreads();

  f32x4 accF[4];
#pragma unroll
  for (int i = 0; i < 4; ++i) accF[i] = f32x4{0.f, 0.f, 0.f, 0.f};
#pragma unroll
  for (int s = 0; s < 2; ++s) {
    const int cc = w * 2 + s;
    const u32x4 b = *(const u32x4*)&sWf[lrow][cc * 32 + kgrp * 8];
#pragma unroll
    for (int i = 0; i < 4; ++i) {
      const u32x4 a = *(const u32x4*)&act[i * 16 + lrow][cc * 32 + kgrp * 8];
      mfma_f16(accF[i], a, b);
    }
  }
#pragma unroll
  for (int i = 0; i < 4; ++i)
#pragma unroll
    for (int r = 0; r < 4; ++r)
      sPart[w][i * 16 + kgrp * 4 + r][lrow] = accF[i][r];
  __syncthreads();

  for (int q = tid; q < 64 * kTargets; q += 256) {
    const int r = q / kTargets, t = q % kTargets;
    out[(size_t)(rowBase + r) * kTargets + t] =
        sPart[0][r][t] + sPart[1][r][t] + sPart[2][r][t] + sPart[3][r][t];
  }
}

// ---------------------------------------------------------------------------
extern "C" void kernel_launch(void* const* d_in, const int* in_sizes, int n_in,
                              void* d_out, int out_size, void* d_ws, size_t ws_size,
                              hipStream_t stream) {
  const float* x      = (const float*)d_in[1];
  const float* rbf    = (const float*)d_in[2];
  const int*   idnb   = (const int*)d_in[3];
  const float* W_rbf  = (const float*)d_in[4];
  const float* W_up   = (const float*)d_in[5];
  const float* W_mlp  = (const float*)d_in[6];
  const float* b_mlp  = (const float*)d_in[7];
  const float* W_fin  = (const float*)d_in[8];
  float* out = (float*)d_out;

  char* wp = (char*)d_ws;
  auto alloc = [&](size_t bytes) -> void* {
    void* r = wp;
    wp += (bytes + 255) & ~(size_t)255;
    return r;
  };
  unsigned short* pooled = (unsigned short*)alloc((size_t)kNodes * kEmb * 2);
  unsigned short* WtUp   = (unsigned short*)alloc(32768 * 2);
  unsigned short* WtM    = (unsigned short*)alloc(3 * 65536 * 2);
  unsigned short* WtFin  = (unsigned short*)alloc(16 * 256 * 2);
  int* counts  = (int*)alloc((size_t)kNodes * 4);
  int* offs    = (int*)alloc((size_t)(kNodes + 8) * 4);
  int* next    = (int*)alloc((size_t)kNodes * 4);
  int* edgeIdx = (int*)alloc((size_t)kEdges * 4);
  int* bsum    = (int*)alloc(256 * 4);

  constexpr int nScanBlk = (kNodes + 255) / 256;  // 157
  constexpr int prepElems = 32768 + 3 * 65536 + 16 * 256;  // 233472

  // Weight images + counts zeroing (one kernel).
  prep_weights<<<(prepElems + 255) / 256, 256, 0, stream>>>(
      W_up, W_mlp, W_fin, WtUp, WtM, WtFin, counts);

  // CSR build.
  hist_kernel<<<kEdges / 256, 256, 0, stream>>>(idnb, counts);
  scan_pass1<<<nScanBlk, 256, 0, stream>>>(counts, bsum);
  scan_pass3<<<nScanBlk, 256, 0, stream>>>(counts, bsum, offs, next, nScanBlk);
  fill_kernel<<<kEdges / 256, 256, 0, stream>>>(idnb, next, edgeIdx);

  // Edge gather -> pooled fp16.
  gather_kernel<<<kNodes / 8, 256, 0, stream>>>(x, rbf, offs, edgeIdx, W_rbf,
                                                pooled);

  // Fused node MLP + final projection (async fragment-order weight staging).
  fused_mlp<<<kNodes / 64, 256, 0, stream>>>(pooled, WtUp, WtM, WtFin, b_mlp,
                                             out);
}